// Round 10
// baseline (11524.142 us; speedup 1.0000x reference)
//
#include <hip/hip_runtime.h>
#include <hip/hip_bf16.h>

// GRU: T=512, B=64, Cin=512, H=1024, 2 layers.
// Round 10: L2-cached broadcast via time-indexed RING buffers. r9's step =
// 5.2us coherent traffic (sc0sc1 = every read is an L3 RTT, 25 GB/s/CU cap)
// + 2.4us barriers. With bid%8 XCD round-robin, each group's h/a set is
// shared by 32 blocks per XCD -> switch h/a reads to PLAIN (L2-cached)
// loads. Coherence without per-phase invalidates (r7's mistake): h/a for
// step t live in ring slot t%16 (fresh addresses; write-through stores),
// one acquire-fence every 8 steps kills recycled-slot stale lines.
// Correct for ANY XCD mapping; locality only affects hit rate.

#define Hh   1024
#define Bz   64
#define Tt   512
#define Mrows (Tt*Bz)   // 32768
#define GBLK 64         // blocks per batch-group barrier
#define SLOT (Bz*Hh)    // ring slot stride (65536 elems)

typedef __attribute__((ext_vector_type(8))) short short8;
typedef __attribute__((ext_vector_type(4))) float f32x4;
typedef __attribute__((ext_vector_type(4))) unsigned int u32x4;
typedef unsigned long long u64;

__device__ __forceinline__ unsigned short f2bf(float f){
  unsigned u = __builtin_bit_cast(unsigned, f);
  u += 0x7fffu + ((u >> 16) & 1u);          // round-to-nearest-even
  return (unsigned short)(u >> 16);
}
__device__ __forceinline__ float bf2f(unsigned short s){
  unsigned u = ((unsigned)s) << 16;
  return __builtin_bit_cast(float, u);
}

// write-through coherent stores (agent scope, relaxed): L3-visible on retire,
// never leave dirty L2 lines.
__device__ __forceinline__ void cstore_u32(void* p, unsigned v){
  __hip_atomic_store((unsigned*)p, v, __ATOMIC_RELAXED, __HIP_MEMORY_SCOPE_AGENT);
}
__device__ __forceinline__ void cstore_u64(void* p, u64 v){
  __hip_atomic_store((u64*)p, v, __ATOMIC_RELAXED, __HIP_MEMORY_SCOPE_AGENT);
}

__device__ __forceinline__ void gload16(const void* g, void* l){
  __builtin_amdgcn_global_load_lds(
      (const __attribute__((address_space(1))) unsigned int*)g,
      (__attribute__((address_space(3))) unsigned int*)l, 16, 0, 0);
}

// fence-free GROUP barrier (64 arrivals): monotonic counter, no reset.
__device__ __forceinline__ void gbar(unsigned* ctr, unsigned* bk){
  __syncthreads();
  *bk += 1;
  if (threadIdx.x == 0){
    __hip_atomic_fetch_add(ctr, 1u, __ATOMIC_RELAXED, __HIP_MEMORY_SCOPE_AGENT);
    const unsigned tgt = (*bk) * GBLK;
    while (__hip_atomic_load(ctr, __ATOMIC_RELAXED, __HIP_MEMORY_SCOPE_AGENT) < tgt)
      __builtin_amdgcn_s_sleep(1);
  }
  __syncthreads();
}

// ---- pipelined loads (PLAIN: L1/L2-cacheable) ----
#define PLOAD16(dst, base, kk) \
  asm volatile("global_load_dwordx4 %0, %1, off offset:%c2" \
               : "=v"(dst) : "v"(base), "i"((kk)*64));
#define PLOADF(dst, addr) \
  asm volatile("global_load_dword %0, %1, off" : "=v"(dst) : "v"(addr));
#define PLOADU16(dst, addr) \
  asm volatile("global_load_ushort %0, %1, off" : "=v"(dst) : "v"(addr));
#define VMWAIT(n) \
  asm volatile("s_waitcnt vmcnt(%c0)" :: "i"(n) : "memory"); \
  __builtin_amdgcn_sched_barrier(0);

// ---------------- prep kernels ----------------

__global__ __launch_bounds__(256) void k_cvt_bf16(const float* __restrict__ src,
                                                  unsigned short* __restrict__ dst, int n4){
  int i = blockIdx.x*blockDim.x + threadIdx.x;
  int stride = gridDim.x*blockDim.x;
  for (; i < n4; i += stride){
    float4 v = reinterpret_cast<const float4*>(src)[i];
    ushort4 o; o.x=f2bf(v.x); o.y=f2bf(v.y); o.z=f2bf(v.z); o.w=f2bf(v.w);
    reinterpret_cast<ushort4*>(dst)[i] = o;
  }
}

// fp32 (K,N) -> bf16 (N,K), 64x64 LDS tile
__global__ __launch_bounds__(256) void k_transpose_bf16(const float* __restrict__ src,
                                                        unsigned short* __restrict__ dst,
                                                        int K, int N){
  __shared__ float tile[64][65];
  int k0 = blockIdx.x * 64, n0 = blockIdx.y * 64;
  int t = threadIdx.x;
  int r = t >> 4, c4 = (t & 15) << 2;
  #pragma unroll
  for (int j = 0; j < 4; ++j){
    const float4 v = *reinterpret_cast<const float4*>(&src[(size_t)(k0 + r + j*16) * N + n0 + c4]);
    tile[r+j*16][c4+0]=v.x; tile[r+j*16][c4+1]=v.y;
    tile[r+j*16][c4+2]=v.z; tile[r+j*16][c4+3]=v.w;
  }
  __syncthreads();
  #pragma unroll
  for (int j = 0; j < 4; ++j){
    int nn = r + j*16;
    ushort4 o;
    o.x = f2bf(tile[c4+0][nn]); o.y = f2bf(tile[c4+1][nn]);
    o.z = f2bf(tile[c4+2][nn]); o.w = f2bf(tile[c4+3][nn]);
    *reinterpret_cast<ushort4*>(&dst[(size_t)(n0+nn)*K + k0 + c4]) = o;
  }
}

__global__ void k_bias_fold(const float* __restrict__ a, const float* __restrict__ b,
                            const float* __restrict__ c, const float* __restrict__ d,
                            float* __restrict__ out){
  int i = blockIdx.x*blockDim.x + threadIdx.x;
  if (i < 2048) out[i] = a[i] + b[i];
  else if (i < 3072) out[i] = c[i-2048] + d[i-2048];
}

// ---------------- big x-projection GEMM ----------------
__global__ __launch_bounds__(256) void k_xproj_gemm(
    const unsigned short* __restrict__ A, const unsigned short* __restrict__ Bt,
    const float* __restrict__ bias, unsigned short* __restrict__ outRZ,
    float* __restrict__ outC, int K)
{
  __shared__ __align__(16) unsigned short As[128*32];
  __shared__ __align__(16) unsigned short Bs[128*32];
  const int nb = blockIdx.x, mb = blockIdx.y;
  const int m0 = mb*128, n0 = nb*128;
  const int t = threadIdx.x, lane = t & 63, w = t >> 6;
  const int wr = w >> 1, wc = w & 1;
  const int lr = lane & 15, lq = lane >> 4;
  const int sr = t >> 2, scg = t & 3;
  f32x4 acc[4][4];
  const f32x4 zero4 = {0.f,0.f,0.f,0.f};
  #pragma unroll
  for (int mt=0;mt<4;++mt)
    #pragma unroll
    for (int nt=0;nt<4;++nt) acc[mt][nt] = zero4;

  const unsigned short* ga0 = &A [(size_t)(m0 + sr     )*K + scg*8];
  const unsigned short* ga1 = &A [(size_t)(m0 + sr + 64)*K + scg*8];
  const unsigned short* gb0 = &Bt[(size_t)(n0 + sr     )*K + scg*8];
  const unsigned short* gb1 = &Bt[(size_t)(n0 + sr + 64)*K + scg*8];
  char* lA = (char*)As + w*1024;
  char* lB = (char*)Bs + w*1024;
  const int kiters = K >> 5;
  for (int kt = 0; kt < kiters; ++kt){
    __syncthreads();
    gload16(ga0 + kt*32, lA);
    gload16(ga1 + kt*32, lA + 4096);
    gload16(gb0 + kt*32, lB);
    gload16(gb1 + kt*32, lB + 4096);
    asm volatile("s_waitcnt vmcnt(0)" ::: "memory");
    __syncthreads();
    short8 af[4], bfr[4];
    #pragma unroll
    for (int mt=0; mt<4; ++mt)
      af[mt] = *reinterpret_cast<const short8*>(&As[(wr*64 + mt*16 + lr)*32 + lq*8]);
    #pragma unroll
    for (int nt=0; nt<4; ++nt)
      bfr[nt] = *reinterpret_cast<const short8*>(&Bs[(wc*64 + nt*16 + lr)*32 + lq*8]);
    #pragma unroll
    for (int mt=0; mt<4; ++mt)
      #pragma unroll
      for (int nt=0; nt<4; ++nt)
        acc[mt][nt] = __builtin_amdgcn_mfma_f32_16x16x32_bf16(af[mt], bfr[nt], acc[mt][nt], 0,0,0);
  }
  const bool isRZ = (n0 < 2048);
  #pragma unroll
  for (int mt=0;mt<4;++mt){
    #pragma unroll
    for (int nt=0;nt<4;++nt){
      int gn = n0 + wc*64 + nt*16 + lr;
      float bv = bias[gn];
      #pragma unroll
      for (int i=0;i<4;++i){
        int gm = m0 + wr*64 + mt*16 + lq*4 + i;
        float v = acc[mt][nt][i] + bv;
        if (isRZ) outRZ[(size_t)gm*2048 + gn] = f2bf(v);
        else      outC [(size_t)gm*1024 + (gn - 2048)] = v;
      }
    }
  }
}

// ---------------- persistent per-layer recurrent kernel ----------------
// 256 blocks x 512 threads. Block (g,c): batch rows [16g,16g+16) x cols
// [16c,16c+16). Cross-block h/a go through 16-slot rings (slot = t%16),
// written write-through, read with plain cached loads; acquire-fence every
// 8 steps invalidates recycled-slot stale lines. Per-group 64-arrival
// barrier (r9). 8 waves = K-slices of 128, LDS combine.
__global__ __launch_bounds__(512) void k_gru_layer(
    const unsigned short* __restrict__ Wrzg,   // (2048,1024) bf16
    const unsigned short* __restrict__ Whhg,   // (1024,1024) bf16
    const unsigned short* __restrict__ XprojRZ,// (T,64,2048) bf16, biases folded
    const float* __restrict__ XprojC,          // (T,64,1024) fp32, biases folded
    unsigned short* ringH, unsigned short* ringHL,   // h rings (16 slots)
    unsigned short* ringA, unsigned short* ringAL,   // a rings (16 slots)
    unsigned short* __restrict__ h0seq,        // L0: bf16 sequence out (else null)
    float* __restrict__ outseq,                // L1: fp32 sequence out (else null)
    float* __restrict__ hn,                    // final h slot
    unsigned* bar)                             // 4 counters, 256B apart
{
  __shared__ __align__(16) unsigned short WrzS[32*1024]; // 64KB rows0-15=r,16-31=z
  __shared__ __align__(16) unsigned short WhhS[16*1024]; // 32KB
  __shared__ float hloc[16][17];                         // block's fp32 h tile
  __shared__ float zloc[16][17];                         // block's z tile
  __shared__ float part[8][64][9];                       // 8-wave K-combine

  const int bid = blockIdx.x;
  const int g = bid & 3;          // batch group (rows 16g..16g+16)
  const int c = bid >> 2;         // column group (cols 16c..16c+16)
  const int tid = threadIdx.x;
  const int lane = tid & 63, w = tid >> 6;
  const int lr = lane & 15, lq = lane >> 4;
  unsigned* ctr = bar + g*64;     // this group's counter (own cacheline)
  unsigned bk = 0;

  // ---- stage weights into LDS (once), XOR-swizzled ----
  #pragma unroll
  for (int j = 0; j < 8; ++j){
    int lin = (tid + j*512) * 8;
    int n = lin >> 10, k = lin & 1023;
    int gr = (n < 16) ? (16*c + n) : (1024 + 16*c + (n - 16));
    short8 v = *reinterpret_cast<const short8*>(&Wrzg[(size_t)gr*1024 + k]);
    *reinterpret_cast<short8*>(&WrzS[(n*1024 + k) ^ ((n&7)<<3)]) = v;
  }
  #pragma unroll
  for (int j = 0; j < 4; ++j){
    int lin = (tid + j*512) * 8;
    int n = lin >> 10, k = lin & 1023;
    short8 v = *reinterpret_cast<const short8*>(&Whhg[(size_t)(16*c + n)*1024 + k]);
    *reinterpret_cast<short8*>(&WhhS[(n*1024 + k) ^ ((n&7)<<3)]) = v;
  }
  // ---- zero local h tile and ring slot 15 (h at t=-1); ws is poisoned ----
  for (int idx = tid; idx < 16*17; idx += 512) ((float*)hloc)[idx] = 0.f;
  if (tid < 128){
    int r = tid >> 3, cp = (tid & 7) * 2;
    cstore_u32(&ringH [(size_t)15*SLOT + (16*g + r)*1024 + 16*c + cp], 0u);
    cstore_u32(&ringHL[(size_t)15*SLOT + (16*g + r)*1024 + 16*c + cp], 0u);
  }
  gbar(ctr, &bk);

  const int kb = 128 * w;   // this wave's K-slice

  for (int t = 0; t < Tt; ++t){
    // drop any cached lines from recycled ring slots (period 8 < reuse 16)
    if ((t & 7) == 0) __builtin_amdgcn_fence(__ATOMIC_ACQUIRE, "agent");
    const size_t hoff = (size_t)((t + 15) & 15) * SLOT;  // h written at t-1
    const size_t soff = (size_t)(t & 15) * SLOT;         // this step's a & h
    // ================= phase A: rz preact + gates =================
    {
      const unsigned short* xp = XprojRZ + (size_t)t*Bz*2048;
      // wave 0: r-col xproj scalars; wave 1: z-col (issued FIRST for vmcnt parity)
      unsigned xv[4];
      if (w == 0){
        #pragma unroll
        for (int i = 0; i < 4; ++i)
          PLOADU16(xv[i], &xp[(16*g + lq*4 + i)*2048 + 16*c + lr]);
      } else if (w == 1){
        #pragma unroll
        for (int i = 0; i < 4; ++i)
          PLOADU16(xv[i], &xp[(16*g + lq*4 + i)*2048 + 1024 + 16*c + lr]);
      }
      const unsigned short* hhp = ringH  + hoff + (size_t)(16*g + lr)*1024 + kb + lq*8;
      const unsigned short* hlp = ringHL + hoff + (size_t)(16*g + lr)*1024 + kb + lq*8;
      u32x4 ahv[4], alv[4];
      #pragma unroll
      for (int s = 0; s < 4; ++s){ PLOAD16(ahv[s], hhp, s) PLOAD16(alv[s], hlp, s) }
      f32x4 accr0={0,0,0,0}, accr1={0,0,0,0}, accz0={0,0,0,0}, accz1={0,0,0,0};
      #pragma unroll
      for (int k = 0; k < 4; ++k){
        VMWAIT(6 - 2*k)   // same closed form for all waves (extra scalars lead)
        short8 ah = __builtin_bit_cast(short8, ahv[k]);
        short8 al = __builtin_bit_cast(short8, alv[k]);
        short8 br = *reinterpret_cast<const short8*>(
            &WrzS[(lr*1024 + kb + k*32 + lq*8) ^ ((lr&7)<<3)]);
        short8 bz = *reinterpret_cast<const short8*>(
            &WrzS[((16+lr)*1024 + kb + k*32 + lq*8) ^ ((lr&7)<<3)]);
        accr0 = __builtin_amdgcn_mfma_f32_16x16x32_bf16(ah, br, accr0, 0,0,0);
        accr1 = __builtin_amdgcn_mfma_f32_16x16x32_bf16(al, br, accr1, 0,0,0);
        accz0 = __builtin_amdgcn_mfma_f32_16x16x32_bf16(ah, bz, accz0, 0,0,0);
        accz1 = __builtin_amdgcn_mfma_f32_16x16x32_bf16(al, bz, accz1, 0,0,0);
      }
      #pragma unroll
      for (int i = 0; i < 4; ++i){
        part[w][lane][i]   = accr0[i] + accr1[i];
        part[w][lane][4+i] = accz0[i] + accz1[i];
      }
      __syncthreads();
      if (w == 0){          // r-gate + a = h*r
        #pragma unroll
        for (int i = 0; i < 4; ++i){
          float s_ = 0.f;
          #pragma unroll
          for (int ww = 0; ww < 8; ++ww) s_ += part[ww][lane][i];
          int row = lq*4 + i;
          float pr = s_ + bf2f((unsigned short)xv[i]);
          float rg = 1.f / (1.f + __expf(-pr));
          float av = hloc[row][lr] * rg;
          unsigned short hi = f2bf(av);
          unsigned short lo = f2bf(av - bf2f(hi));
          unsigned hi2 = (unsigned)__shfl_down((int)hi, 1) & 0xffffu;
          unsigned lo2 = (unsigned)__shfl_down((int)lo, 1) & 0xffffu;
          if (!(lane & 1)){
            cstore_u32(&ringA [soff + (size_t)(16*g + row)*1024 + 16*c + lr],
                       (unsigned)hi | (hi2<<16));
            cstore_u32(&ringAL[soff + (size_t)(16*g + row)*1024 + 16*c + lr],
                       (unsigned)lo | (lo2<<16));
          }
        }
      } else if (w == 1){   // z-gate
        #pragma unroll
        for (int i = 0; i < 4; ++i){
          float s_ = 0.f;
          #pragma unroll
          for (int ww = 0; ww < 8; ++ww) s_ += part[ww][lane][4+i];
          int row = lq*4 + i;
          float pz = s_ + bf2f((unsigned short)xv[i]);
          zloc[row][lr] = 1.f / (1.f + __expf(-pz));
        }
      }
    }
    gbar(ctr, &bk);
    // ================= phase B: cand + state update =================
    {
      const float* xc = XprojC + (size_t)t*Bz*1024;
      float xcv[4];
      if (w == 0){
        #pragma unroll
        for (int i = 0; i < 4; ++i)
          PLOADF(xcv[i], &xc[(16*g + lq*4 + i)*1024 + 16*c + lr]);
      }
      const unsigned short* ahp = ringA  + soff + (size_t)(16*g + lr)*1024 + kb + lq*8;
      const unsigned short* alp = ringAL + soff + (size_t)(16*g + lr)*1024 + kb + lq*8;
      u32x4 ahv[4], alv[4];
      #pragma unroll
      for (int s = 0; s < 4; ++s){ PLOAD16(ahv[s], ahp, s) PLOAD16(alv[s], alp, s) }
      f32x4 acc0={0,0,0,0}, acc1={0,0,0,0};
      #pragma unroll
      for (int k = 0; k < 4; ++k){
        VMWAIT(6 - 2*k)
        short8 ah = __builtin_bit_cast(short8, ahv[k]);
        short8 al = __builtin_bit_cast(short8, alv[k]);
        short8 bb = *reinterpret_cast<const short8*>(
            &WhhS[(lr*1024 + kb + k*32 + lq*8) ^ ((lr&7)<<3)]);
        acc0 = __builtin_amdgcn_mfma_f32_16x16x32_bf16(ah, bb, acc0, 0,0,0);
        acc1 = __builtin_amdgcn_mfma_f32_16x16x32_bf16(al, bb, acc1, 0,0,0);
      }
      #pragma unroll
      for (int i = 0; i < 4; ++i) part[w][lane][i] = acc0[i] + acc1[i];
      __syncthreads();
      if (w == 0){
        #pragma unroll
        for (int i = 0; i < 4; ++i){
          float s_ = 0.f;
          #pragma unroll
          for (int ww = 0; ww < 8; ++ww) s_ += part[ww][lane][i];
          int row = lq*4 + i;
          int grow = 16*g + row, gcol = 16*c + lr;
          float pre = s_ + xcv[i];
          float cand = tanhf(pre);
          float zg = zloc[row][lr];
          float h  = hloc[row][lr];
          float hnew = zg*h + (1.f - zg)*cand;
          hloc[row][lr] = hnew;
          unsigned short hi = f2bf(hnew);
          unsigned short lo = f2bf(hnew - bf2f(hi));
          unsigned hi2 = (unsigned)__shfl_down((int)hi, 1) & 0xffffu;
          unsigned lo2 = (unsigned)__shfl_down((int)lo, 1) & 0xffffu;
          float hnew2 = __shfl_down(hnew, 1);
          if (!(lane & 1)){
            cstore_u32(&ringH [soff + (size_t)grow*1024 + gcol], (unsigned)hi | (hi2<<16));
            cstore_u32(&ringHL[soff + (size_t)grow*1024 + gcol], (unsigned)lo | (lo2<<16));
            if (h0seq)
              cstore_u32(&h0seq[(size_t)t*(Bz*Hh) + grow*1024 + gcol],
                         (unsigned)hi | (hi2<<16));
            if (outseq){
              float2 pr2 = {hnew, hnew2};
              cstore_u64(&outseq[(size_t)t*(Bz*Hh) + grow*1024 + gcol],
                         __builtin_bit_cast(u64, pr2));
            }
            if (t == Tt-1){
              float2 pr2 = {hnew, hnew2};
              cstore_u64(&hn[(size_t)grow*1024 + gcol], __builtin_bit_cast(u64, pr2));
            }
          }
        }
      }
    }
    gbar(ctr, &bk);
  }
}

// ---------------- host ----------------

extern "C" void kernel_launch(void* const* d_in, const int* in_sizes, int n_in,
                              void* d_out, int out_size, void* d_ws, size_t ws_size,
                              hipStream_t stream)
{
  (void)in_sizes; (void)n_in; (void)out_size; (void)ws_size;
  const float* X     = (const float*)d_in[0];
  const float* Wxrz0 = (const float*)d_in[1];
  const float* bxrz0 = (const float*)d_in[2];
  const float* Whrz0 = (const float*)d_in[3];
  const float* bhrz0 = (const float*)d_in[4];
  const float* Wxh0  = (const float*)d_in[5];
  const float* bxh0  = (const float*)d_in[6];
  const float* Whh0  = (const float*)d_in[7];
  const float* bhh0  = (const float*)d_in[8];
  const float* Wxrz1 = (const float*)d_in[9];
  const float* bxrz1 = (const float*)d_in[10];
  const float* Whrz1 = (const float*)d_in[11];
  const float* bhrz1 = (const float*)d_in[12];
  const float* Wxh1  = (const float*)d_in[13];
  const float* bxh1  = (const float*)d_in[14];
  const float* Whh1  = (const float*)d_in[15];
  const float* bhh1  = (const float*)d_in[16];

  char* p = (char*)d_ws;
  auto carve = [&](size_t bytes)->char*{
    char* r = p; p += (bytes + 255) & ~(size_t)255; return r;
  };
  unsigned short* Xbf    = (unsigned short*)carve((size_t)Mrows*512*2);
  unsigned short* W0t    = (unsigned short*)carve((size_t)3072*512*2);
  unsigned short* W1t    = (unsigned short*)carve((size_t)3072*1024*2);
  unsigned short* Whrz0t = (unsigned short*)carve((size_t)2048*1024*2);
  unsigned short* Whh0t  = (unsigned short*)carve((size_t)1024*1024*2);
  unsigned short* Whrz1t = (unsigned short*)carve((size_t)2048*1024*2);
  unsigned short* Whh1t  = (unsigned short*)carve((size_t)1024*1024*2);
  float* bias0 = (float*)carve(3072*4);
  float* bias1 = (float*)carve(3072*4);
  unsigned short* XprojRZ = (unsigned short*)carve((size_t)Mrows*2048*2);
  float*          XprojC  = (float*)carve((size_t)Mrows*1024*4);
  unsigned short* H0seq   = (unsigned short*)carve((size_t)Mrows*1024*2);
  unsigned* bar = (unsigned*)carve(2048);   // L0: 4 counters @256B; L1: +1024B

  // rings alias the Xbf region (dead after the first xproj GEMM):
  // 4 rings x 16 slots x 64K elems x 2B = 8 MB << 32 MB Xbf.
  unsigned short* ringH  = Xbf;
  unsigned short* ringHL = Xbf + (size_t)16*SLOT;
  unsigned short* ringA  = Xbf + (size_t)32*SLOT;
  unsigned short* ringAL = Xbf + (size_t)48*SLOT;

  hipMemsetAsync(bar, 0, 2048, stream);

  k_cvt_bf16<<<2048,256,0,stream>>>(X, Xbf, Mrows*512/4);
  k_transpose_bf16<<<dim3(8,32), 256,0,stream>>>(Wxrz0, W0t, 512, 2048);
  k_transpose_bf16<<<dim3(8,16), 256,0,stream>>>(Wxh0,  W0t + (size_t)2048*512, 512, 1024);
  k_transpose_bf16<<<dim3(16,32),256,0,stream>>>(Whrz0, Whrz0t, 1024, 2048);
  k_transpose_bf16<<<dim3(16,16),256,0,stream>>>(Whh0,  Whh0t, 1024, 1024);
  k_transpose_bf16<<<dim3(16,32),256,0,stream>>>(Wxrz1, W1t, 1024, 2048);
  k_transpose_bf16<<<dim3(16,16),256,0,stream>>>(Wxh1,  W1t + (size_t)2048*1024, 1024, 1024);
  k_transpose_bf16<<<dim3(16,32),256,0,stream>>>(Whrz1, Whrz1t, 1024, 2048);
  k_transpose_bf16<<<dim3(16,16),256,0,stream>>>(Whh1,  Whh1t, 1024, 1024);
  k_bias_fold<<<12,256,0,stream>>>(bxrz0, bhrz0, bxh0, bhh0, bias0);
  k_bias_fold<<<12,256,0,stream>>>(bxrz1, bhrz1, bxh1, bhh1, bias1);

  float* out = (float*)d_out;
  float* hn0 = out + (size_t)Mrows*Hh;
  float* hn1 = hn0 + Bz*Hh;

  // ---- layer 0 ----
  k_xproj_gemm<<<dim3(24,256),256,0,stream>>>(Xbf, W0t, bias0, XprojRZ, XprojC, 512);
  k_gru_layer<<<256,512,0,stream>>>(Whrz0t, Whh0t, XprojRZ, XprojC,
                                    ringH, ringHL, ringA, ringAL,
                                    H0seq, nullptr, hn0, bar);
  // ---- layer 1 ----
  k_xproj_gemm<<<dim3(24,256),256,0,stream>>>(H0seq, W1t, bias1, XprojRZ, XprojC, 1024);
  k_gru_layer<<<256,512,0,stream>>>(Whrz1t, Whh1t, XprojRZ, XprojC,
                                    ringH, ringHL, ringA, ringAL,
                                    nullptr, out, hn1, bar + 256);
}